// Round 5
// baseline (468.045 us; speedup 1.0000x reference)
//
#include <hip/hip_runtime.h>
#include <math.h>
#include <stdint.h>
#include <stddef.h>

typedef _Float16 f16;
typedef _Float16 f16x8 __attribute__((ext_vector_type(8)));
typedef _Float16 f16x4 __attribute__((ext_vector_type(4)));
typedef __fp16 fp16x2 __attribute__((ext_vector_type(2)));
typedef float f32x4 __attribute__((ext_vector_type(4)));
typedef float fvec4 __attribute__((ext_vector_type(4)));
typedef unsigned int u32x4 __attribute__((ext_vector_type(4)));

#define MFMA16F16(a, b, c) __builtin_amdgcn_mfma_f32_16x16x32_f16((a), (b), (c), 0, 0, 0)

static constexpr int kT = 2048;
static constexpr int kB = 4;
static constexpr int kD = 1024;
static constexpr int kNH = 16;
static constexpr int kM = kB * kT;  // 8192
static constexpr int kMAXL = 100;
static constexpr float kLOG2E = 1.4426950408889634f;

// ---------------- workspace layout (bytes) ----------------
static constexpr size_t SZ_XH = (size_t)kM * kD * 2;  // 16 MB fp16
static constexpr size_t SZ_W = (size_t)kD * kD * 2;   // 2 MB fp16
static constexpr size_t OFF_TAB = 0;                  // 16*101 floats + (1-w)
static constexpr size_t OFF_BQK = 8192;               // concat [bq|bk] (2048 f32)
static constexpr size_t OFF_PRE = 16384;              // V prefix sums 64*17*64 f32
static constexpr size_t OFF_XH = OFF_PRE + 64 * 17 * 64 * 4;  // 294912
static constexpr size_t OFF_WQ = OFF_XH + SZ_XH;
static constexpr size_t OFF_WK = OFF_WQ + SZ_W;  // MUST stay adjacent to WQ (fused QK gemm)
static constexpr size_t OFF_WV = OFF_WK + SZ_W;
static constexpr size_t OFF_WF = OFF_WV + SZ_W;
static constexpr size_t OFF_QK = OFF_WF + SZ_W;       // [8192][2048] fp16 (Q | K)
static constexpr size_t OFF_V = OFF_QK + 2 * SZ_XH;   // V^T [1024][8192]
static constexpr size_t OFF_P = OFF_V + SZ_XH;        // blended (blend@V) fp16
static constexpr size_t WS_NEED = OFF_P + SZ_XH;      // ~88.3 MB

__device__ __forceinline__ unsigned int pk_f16(float a, float b) {
  fp16x2 h = __builtin_amdgcn_cvt_pkrtz(a, b);
  return __builtin_bit_cast(unsigned int, h);
}

// ---------------- P table + concat bias ----------------
__global__ void mk_tab_kernel(const float* __restrict__ mu, const float* __restrict__ lam,
                              const float* __restrict__ g1, const float* __restrict__ g2,
                              const float* __restrict__ th1, const float* __restrict__ th2,
                              const float* __restrict__ bq, const float* __restrict__ bk,
                              float* __restrict__ tab, float* __restrict__ bqk) {
  const float w = 1.0f / (1.0f + expf(-mu[0]));
  for (int e = threadIdx.x; e < kNH * (kMAXL + 1); e += blockDim.x) {
    const int h = e / (kMAXL + 1);
    const int L = e - h * (kMAXL + 1);
    const float Lf = (float)L;
    float v;
    if (h < 4) {
      const float base = lam[h];
      const float mag = expf(Lf * logf(fabsf(base)));
      const float sgn = (base < 0.0f && (L & 1)) ? -1.0f : 1.0f;
      v = mag * sgn;
    } else if (h < 10) {
      const int s = h - 4;
      v = expf(Lf * logf(g1[s])) * sinf(th1[s] * Lf);
    } else {
      const int s = h - 10;
      v = expf(Lf * logf(g2[s])) * cosf(th2[s] * Lf);
    }
    tab[e] = w * v;
  }
  if (threadIdx.x == 0) tab[kNH * (kMAXL + 1)] = 1.0f - w;
  for (int i = threadIdx.x; i < 2 * kD; i += blockDim.x)
    bqk[i] = (i < kD) ? bq[i] : bk[i - kD];
}

// ---------------- fp32 -> fp16 convert ----------------
__global__ void cvt_kernel(const float* __restrict__ s, f16* __restrict__ d, int n4) {
  int i = blockIdx.x * blockDim.x + threadIdx.x;
  const int stride = gridDim.x * blockDim.x;
  for (; i < n4; i += stride) {
    fvec4 v = ((const fvec4*)s)[i];
    f16x4 o;
    o[0] = (f16)v[0]; o[1] = (f16)v[1]; o[2] = (f16)v[2]; o[3] = (f16)v[3];
    ((f16x4*)d)[i] = o;
  }
}

// ---------------- V column prefix sums ----------------
// Pre[combo][tI][d] = sum_{j < tI*128} Vt[h*64+d][bi*2048 + j], combo = bi*16+h, tI in 0..16
__global__ void vsum_kernel(const f16* __restrict__ Vt, float* __restrict__ Pre) {
  const int combo = blockIdx.x;
  const int h = combo & 15;
  const int bi = combo >> 4;
  const int d = threadIdx.x;  // 64 threads
  const f16* row = Vt + (size_t)(h * 64 + d) * kM + bi * kT;
  float run = 0.f;
  Pre[(combo * 17 + 0) * 64 + d] = 0.f;
  for (int tI = 0; tI < 16; tI++) {
    float s = 0.f;
    for (int j = 0; j < 128; j += 8) {
      f16x8 v = *(const f16x8*)(row + tI * 128 + j);
      s += ((float)v[0] + (float)v[1]) + ((float)v[2] + (float)v[3]) +
           ((float)v[4] + (float)v[5]) + ((float)v[6] + (float)v[7]);
    }
    run += s;
    Pre[(combo * 17 + tI + 1) * 64 + d] = run;
  }
}

// ---------------- C[m,n] = sum_k A[m,k]*B[n,k] (+bias) * scale(col) ----------------
// 128x128 tile, BK=32, 4 waves each 64x64, 16x16x32 f16 MFMA, register-prefetch staging.
// scale = (gc < nsplit) ? os0 : os1 (per-column, for the fused Q|K projection).
template <typename OutT, bool BIAS_ROW>
__global__ __launch_bounds__(256, 2) void gemm_bt_kernel(
    const f16* __restrict__ A, const f16* __restrict__ B, const float* __restrict__ bias,
    OutT* __restrict__ C, int M, int N, int K, int nsplit, float os0, float os1) {
  __shared__ f16 As[128][32];
  __shared__ f16 Bs[128][32];
  const int tid = threadIdx.x;
  const int lane = tid & 63;
  const int wave = tid >> 6;
  const int quad = lane >> 4;
  const int l16 = lane & 15;
  const int nb = N >> 7;
  const int bm = blockIdx.x / nb;
  const int bn = blockIdx.x - bm * nb;
  const int m0 = bm << 7;
  const int n0 = bn << 7;
  const int wm = (wave & 1) << 6;
  const int wn = (wave >> 1) << 6;

  const int srow = tid >> 2;        // 0..63
  const int scol = (tid & 3) << 3;  // 0,8,16,24
  const f16* Ap = A + (size_t)(m0 + srow) * K + scol;
  const f16* Bp = B + (size_t)(n0 + srow) * K + scol;
  const size_t rstep = (size_t)64 * K;

  f32x4 acc[4][4];
#pragma unroll
  for (int i = 0; i < 4; i++)
#pragma unroll
    for (int j = 0; j < 4; j++) acc[i][j] = (f32x4){0.f, 0.f, 0.f, 0.f};

  f16x8 ra0 = *(const f16x8*)(Ap);
  f16x8 ra1 = *(const f16x8*)(Ap + rstep);
  f16x8 rb0 = *(const f16x8*)(Bp);
  f16x8 rb1 = *(const f16x8*)(Bp + rstep);

  for (int k0 = 0; k0 < K; k0 += 32) {
    __syncthreads();
    *(f16x8*)&As[srow][scol] = ra0;
    *(f16x8*)&As[srow + 64][scol] = ra1;
    *(f16x8*)&Bs[srow][scol] = rb0;
    *(f16x8*)&Bs[srow + 64][scol] = rb1;
    __syncthreads();
    if (k0 + 32 < K) {  // prefetch next K-slab while computing
      ra0 = *(const f16x8*)(Ap + (k0 + 32));
      ra1 = *(const f16x8*)(Ap + rstep + (k0 + 32));
      rb0 = *(const f16x8*)(Bp + (k0 + 32));
      rb1 = *(const f16x8*)(Bp + rstep + (k0 + 32));
    }
    f16x8 af[4], bf[4];
#pragma unroll
    for (int i = 0; i < 4; i++) af[i] = *(const f16x8*)&As[wm + i * 16 + l16][quad * 8];
#pragma unroll
    for (int i = 0; i < 4; i++) bf[i] = *(const f16x8*)&Bs[wn + i * 16 + l16][quad * 8];
#pragma unroll
    for (int mi = 0; mi < 4; mi++)
#pragma unroll
      for (int ni = 0; ni < 4; ni++) acc[mi][ni] = MFMA16F16(af[mi], bf[ni], acc[mi][ni]);
  }

#pragma unroll
  for (int mi = 0; mi < 4; mi++) {
    const int rbase = m0 + wm + mi * 16 + quad * 4;
#pragma unroll
    for (int ni = 0; ni < 4; ni++) {
      const int gc = n0 + wn + ni * 16 + l16;
      const float bcol = BIAS_ROW ? 0.0f : bias[gc];
      const float osc = (gc < nsplit) ? os0 : os1;
#pragma unroll
      for (int r = 0; r < 4; r++) {
        const int gr = rbase + r;
        float v = acc[mi][ni][r] + (BIAS_ROW ? bias[gr] : bcol);
        v *= osc;
        C[(size_t)gr * N + gc] = (OutT)v;
      }
    }
  }
}

// ---------------- fused attention + positional blend (S^T formulation) ----------------
// grid: 1024 blocks = 16 qt x (16 h x 4 bi), XCD-swizzled (combo&7 -> XCD) so each XCD's
// 8 (bi,h) combos' K+V (512 KB each) stay L2-resident.
// K tile: double-buffered LDS with register prefetch -> ONE barrier per j-tile.
// V: direct global f16x8 fragment loads (L1-shared across the block's waves, L2-affine).
// Const positional region (all tab[100], block-uniform: tiles j0 <= qblk-256) comes from
// precomputed V prefix sums instead of MFMAs; near-diagonal band (2 tiles) post-loop.
__global__ __launch_bounds__(256, 4) void attn_kernel(
    const f16* __restrict__ QK, const f16* __restrict__ Vt, const float* __restrict__ tabg,
    const float* __restrict__ Pre, f16* __restrict__ Pb) {
  __shared__ f16 Ks[2][128][72];  // K tile [j][d], +8 pad
  __shared__ float tab_s[101];

  const int tid = threadIdx.x;
  const int lane = tid & 63;
  const int wave = tid >> 6;
  const int qd = lane >> 4;
  const int l16 = lane & 15;
  // XCD-affinity decode
  const int xcd = blockIdx.x & 7;
  const int rest = blockIdx.x >> 3;         // 0..127
  const int qt = rest & 15;
  const int combo = (rest >> 4) * 8 + xcd;  // 0..63 == bi*16 + h
  const int h = combo & 15;
  const int bi = combo >> 4;

  if (tid < 101) tab_s[tid] = tabg[h * 101 + tid];
  const float one_m_w = tabg[kNH * 101];
  const float tab100f = tabg[h * 101 + kMAXL];

  const int qblk = qt * 128;
  const int q0 = qblk + wave * 32;  // t-local
  const int bt0 = bi * kT;
  const f16* Qb = QK + (size_t)bt0 * (2 * kD) + h * 64;
  const f16* Kb = QK + (size_t)bt0 * (2 * kD) + kD + h * 64;
  const f16* Vb = Vt + (size_t)(h * 64) * kM + bt0;  // row d, stride kM

  // Q fragments (B-operand layout) straight from global; live whole kernel
  f16x8 qf[2][2];
#pragma unroll
  for (int mi = 0; mi < 2; mi++)
#pragma unroll
    for (int kc = 0; kc < 2; kc++)
      qf[mi][kc] = *(const f16x8*)(Qb + (size_t)(q0 + mi * 16 + l16) * (2 * kD) + kc * 32 + qd * 8);

  f32x4 Oa[2][4];
#pragma unroll
  for (int nt = 0; nt < 4; nt++) {
    Oa[0][nt] = (f32x4){0.f, 0.f, 0.f, 0.f};
    Oa[1][nt] = (f32x4){0.f, 0.f, 0.f, 0.f};
  }
  float mrow[2] = {-INFINITY, -INFINITY};
  float lrow[2] = {0.f, 0.f};

  const int lA = ((qd & 1) << 5) + l16;
  const int lB = lA + 16;
  const bool hiT = qd >= 2;

  // K staging: thread covers row krow, 4x16B chunks
  const int krow = tid >> 1;
  const int kcol = (tid & 1) * 32;
  f16x8 kst[4];
#pragma unroll
  for (int u = 0; u < 4; u++)
    kst[u] = *(const f16x8*)(Kb + (size_t)krow * (2 * kD) + kcol + u * 8);

  for (int t = 0; t < 16; t++) {
    const int j0 = t * 128;
    // write staged tile t into buffer t&1
#pragma unroll
    for (int u = 0; u < 4; u++) *(f16x8*)&Ks[t & 1][krow][kcol + u * 8] = kst[u];
    if (t < 15) {  // prefetch tile t+1 (covers the whole compute phase)
      const int j1 = j0 + 128;
#pragma unroll
      for (int u = 0; u < 4; u++)
        kst[u] = *(const f16x8*)(Kb + (size_t)(j1 + krow) * (2 * kD) + kcol + u * 8);
    }
    __syncthreads();  // buffer t&1 visible; prior reads of this buffer (t-2) long done

#pragma unroll
    for (int c = 0; c < 2; c++) {  // 64-j chunks
      // S^T = K Q^T
      f32x4 s[2][4];
#pragma unroll
      for (int mi = 0; mi < 2; mi++)
#pragma unroll
        for (int ni = 0; ni < 4; ni++) s[mi][ni] = (f32x4){0.f, 0.f, 0.f, 0.f};
#pragma unroll
      for (int kc = 0; kc < 2; kc++) {
#pragma unroll
        for (int ni = 0; ni < 4; ni++) {
          f16x8 kf = *(const f16x8*)&Ks[t & 1][c * 64 + ni * 16 + l16][kc * 32 + qd * 8];
          s[0][ni] = MFMA16F16(kf, qf[0][kc], s[0][ni]);
          s[1][ni] = MFMA16F16(kf, qf[1][kc], s[1][ni]);
        }
      }

      unsigned int pk2[2][4][2];
#pragma unroll
      for (int mi = 0; mi < 2; mi++) {
        float mx = s[mi][0][0];
#pragma unroll
        for (int ni = 0; ni < 4; ni++)
#pragma unroll
          for (int r = 0; r < 4; r++) mx = fmaxf(mx, s[mi][ni][r]);
        mx = fmaxf(mx, __shfl_xor(mx, 16));
        mx = fmaxf(mx, __shfl_xor(mx, 32));
        const float mnew = fmaxf(mrow[mi], mx);
        const float al = __builtin_amdgcn_exp2f(mrow[mi] - mnew);
        mrow[mi] = mnew;
        if (__any(al < 1.0f)) {
          float ar[4];
#pragma unroll
          for (int r = 0; r < 4; r++) ar[r] = __shfl(al, qd * 4 + r);
#pragma unroll
          for (int nt = 0; nt < 4; nt++)
#pragma unroll
            for (int r = 0; r < 4; r++) Oa[mi][nt][r] *= ar[r];
        }
        float lsum = 0.f;
#pragma unroll
        for (int ni = 0; ni < 4; ni++) {
          const float e0 = __builtin_amdgcn_exp2f(s[mi][ni][0] - mnew);
          const float e1 = __builtin_amdgcn_exp2f(s[mi][ni][1] - mnew);
          const float e2 = __builtin_amdgcn_exp2f(s[mi][ni][2] - mnew);
          const float e3 = __builtin_amdgcn_exp2f(s[mi][ni][3] - mnew);
          lsum += (e0 + e1) + (e2 + e3);
          pk2[mi][ni][0] = pk_f16(e0, e1);
          pk2[mi][ni][1] = pk_f16(e2, e3);
        }
        lsum += __shfl_xor(lsum, 16);
        lsum += __shfl_xor(lsum, 32);
        lrow[mi] = lrow[mi] * al + lsum;
      }

      // exchange C-layout exp(S^T) -> A-fragments, then O += P @ V (V direct from global)
#pragma unroll
      for (int kc2 = 0; kc2 < 2; kc2++) {
        f16x8 af[2];
#pragma unroll
        for (int mi = 0; mi < 2; mi++) {
          const unsigned int a0 = __shfl(pk2[mi][2 * kc2][0], lA);
          const unsigned int a1 = __shfl(pk2[mi][2 * kc2][1], lA);
          const unsigned int a2 = __shfl(pk2[mi][2 * kc2][0], lB);
          const unsigned int a3 = __shfl(pk2[mi][2 * kc2][1], lB);
          const unsigned int b0 = __shfl(pk2[mi][2 * kc2 + 1][0], lA);
          const unsigned int b1 = __shfl(pk2[mi][2 * kc2 + 1][1], lA);
          const unsigned int b2 = __shfl(pk2[mi][2 * kc2 + 1][0], lB);
          const unsigned int b3 = __shfl(pk2[mi][2 * kc2 + 1][1], lB);
          u32x4 u;
          u[0] = hiT ? b0 : a0;
          u[1] = hiT ? b1 : a1;
          u[2] = hiT ? b2 : a2;
          u[3] = hiT ? b3 : a3;
          af[mi] = __builtin_bit_cast(f16x8, u);
        }
        const int jc = j0 + c * 64 + kc2 * 32 + qd * 8;
#pragma unroll
        for (int nt = 0; nt < 4; nt++) {
          f16x8 vf = *(const f16x8*)(Vb + (size_t)(nt * 16 + l16) * kM + jc);
          Oa[0][nt] = MFMA16F16(af[0], vf, Oa[0][nt]);
          Oa[1][nt] = MFMA16F16(af[1], vf, Oa[1][nt]);
        }
      }
    }
  }

  // scale attention by (1-w)/l and add const-P contribution from prefix sums
  const int tI = (qt >= 2) ? (qt - 1) : 0;  // prefix over j < qblk-128 (0 for qt<2)
#pragma unroll
  for (int mi = 0; mi < 2; mi++) {
    float lr[4];
#pragma unroll
    for (int r = 0; r < 4; r++) lr[r] = __shfl(lrow[mi], qd * 4 + r);
#pragma unroll
    for (int nt = 0; nt < 4; nt++) {
      const float pre = tab100f * Pre[(combo * 17 + tI) * 64 + nt * 16 + l16];
#pragma unroll
      for (int r = 0; r < 4; r++) Oa[mi][nt][r] = Oa[mi][nt][r] * (one_m_w / lr[r]) + pre;
    }
  }

  // near-diagonal positional band: 2 tiles with table fragments, V direct from global
#pragma unroll
  for (int tb = 0; tb < 2; tb++) {
    const int jb = qblk - 128 + tb * 128;
    if (jb >= 0) {
#pragma unroll
      for (int kc = 0; kc < 4; kc++) {
        f16x8 wf[2];
#pragma unroll
        for (int mi = 0; mi < 2; mi++) {
          const int q = q0 + mi * 16 + l16;
#pragma unroll
          for (int jj = 0; jj < 8; jj++) {
            const int j = jb + kc * 32 + qd * 8 + jj;
            const int dlt = q - j;
            float pv = 0.0f;
            if (dlt > 0) pv = tab_s[dlt > kMAXL ? kMAXL : dlt];
            wf[mi][jj] = (f16)pv;
          }
        }
        const int jc = jb + kc * 32 + qd * 8;
#pragma unroll
        for (int nt = 0; nt < 4; nt++) {
          f16x8 vf = *(const f16x8*)(Vb + (size_t)(nt * 16 + l16) * kM + jc);
          Oa[0][nt] = MFMA16F16(wf[0], vf, Oa[0][nt]);
          Oa[1][nt] = MFMA16F16(wf[1], vf, Oa[1][nt]);
        }
      }
    }
  }

  // store
#pragma unroll
  for (int mi = 0; mi < 2; mi++)
#pragma unroll
    for (int nt = 0; nt < 4; nt++)
#pragma unroll
      for (int r = 0; r < 4; r++) {
        const int q = q0 + mi * 16 + qd * 4 + r;
        Pb[(size_t)(bt0 + q) * kD + h * 64 + nt * 16 + l16] = (f16)Oa[mi][nt][r];
      }
}

extern "C" void kernel_launch(void* const* d_in, const int* in_sizes, int n_in, void* d_out,
                              int out_size, void* d_ws, size_t ws_size, hipStream_t stream) {
  const float* x = (const float*)d_in[0];
  const float* mu = (const float*)d_in[1];
  const float* lam = (const float*)d_in[2];
  const float* g1 = (const float*)d_in[3];
  const float* g2 = (const float*)d_in[4];
  const float* th1 = (const float*)d_in[5];
  const float* th2 = (const float*)d_in[6];
  const float* Wq = (const float*)d_in[7];
  const float* bq = (const float*)d_in[8];
  const float* Wk = (const float*)d_in[9];
  const float* bk = (const float*)d_in[10];
  const float* Wv = (const float*)d_in[11];
  const float* bv = (const float*)d_in[12];
  const float* Wf = (const float*)d_in[13];
  const float* bf = (const float*)d_in[14];

  if (ws_size < WS_NEED) return;  // cannot run without scratch

  char* ws = (char*)d_ws;
  float* tab = (float*)(ws + OFF_TAB);
  float* bqk = (float*)(ws + OFF_BQK);
  float* Pre = (float*)(ws + OFF_PRE);
  f16* xh = (f16*)(ws + OFF_XH);
  f16* wqh = (f16*)(ws + OFF_WQ);
  f16* wkh = (f16*)(ws + OFF_WK);
  f16* wvh = (f16*)(ws + OFF_WV);
  f16* wfh = (f16*)(ws + OFF_WF);
  f16* QKp = (f16*)(ws + OFF_QK);
  f16* Vtp = (f16*)(ws + OFF_V);
  f16* Pbp = (f16*)(ws + OFF_P);

  mk_tab_kernel<<<1, 256, 0, stream>>>(mu, lam, g1, g2, th1, th2, bq, bk, tab, bqk);
  cvt_kernel<<<2048, 256, 0, stream>>>(x, xh, kM * kD / 4);
  cvt_kernel<<<1024, 256, 0, stream>>>(Wq, wqh, kD * kD / 4);
  cvt_kernel<<<1024, 256, 0, stream>>>(Wk, wkh, kD * kD / 4);
  cvt_kernel<<<1024, 256, 0, stream>>>(Wv, wvh, kD * kD / 4);
  cvt_kernel<<<1024, 256, 0, stream>>>(Wf, wfh, kD * kD / 4);

  // Fused Q|K projection: B = [Wq; Wk] (adjacent in ws), bias = [bq|bk],
  // Q columns (<1024) pre-scaled by log2(e) for exp2-domain softmax.
  gemm_bt_kernel<f16, false><<<1024, 256, 0, stream>>>(xh, wqh, bqk, QKp, kM, 2 * kD, kD, kD,
                                                       kLOG2E, 1.0f);
  // V^T = Wv * x^T : swapped operands, bias indexed by row (dim)
  gemm_bt_kernel<f16, true><<<512, 256, 0, stream>>>(wvh, xh, bv, Vtp, kD, kM, kD, kM, 1.0f,
                                                     1.0f);
  vsum_kernel<<<64, 64, 0, stream>>>(Vtp, Pre);

  attn_kernel<<<1024, 256, 0, stream>>>(QKp, Vtp, tab, Pre, Pbp);

  gemm_bt_kernel<float, false><<<512, 256, 0, stream>>>(Pbp, wfh, bf, (float*)d_out, kM, kD, kD,
                                                        kD, 1.0f, 1.0f);
}